// Round 2
// baseline (8617.551 us; speedup 1.0000x reference)
//
#include <hip/hip_runtime.h>
#include <math.h>

#define CIN 64
#define CE  64
#define HH  256
#define WW  256
#define OHW 128

// ---------------- gate: global average pool ----------------
__global__ __launch_bounds__(256)
void pool_kernel(const float* __restrict__ x, float* __restrict__ pooled) {
    int bc = blockIdx.x;  // 0..B*CIN-1
    const float4* p = reinterpret_cast<const float4*>(x + (size_t)bc * (HH * WW));
    float s = 0.f;
    for (int i = threadIdx.x; i < (HH * WW) / 4; i += 256) {
        float4 v = p[i];
        s += (v.x + v.y) + (v.z + v.w);
    }
#pragma unroll
    for (int m = 32; m >= 1; m >>= 1) s += __shfl_xor(s, m, 64);
    __shared__ float red[4];
    int lane = threadIdx.x & 63, wv = threadIdx.x >> 6;
    if (lane == 0) red[wv] = s;
    __syncthreads();
    if (threadIdx.x == 0) {
        float t = (red[0] + red[1]) + (red[2] + red[3]);
        pooled[bc] = t * (1.0f / (HH * WW));
    }
}

// ---------------- gate: linear -> softmax -> top2 ----------------
__global__ __launch_bounds__(64)
void gate_kernel(const float* __restrict__ pooled, const float* __restrict__ gw,
                 const float* __restrict__ gb, int* __restrict__ sel_idx,
                 float* __restrict__ sel_w) {
    int b = blockIdx.x;
    int c = threadIdx.x;  // 0..63 == CIN
    float p = pooled[b * CIN + c];
    float l[4];
#pragma unroll
    for (int e = 0; e < 4; ++e) l[e] = p * gw[e * CIN + c];
#pragma unroll
    for (int m = 32; m >= 1; m >>= 1) {
#pragma unroll
        for (int e = 0; e < 4; ++e) l[e] += __shfl_xor(l[e], m, 64);
    }
    if (c == 0) {
        float g[4], s = 0.f;
#pragma unroll
        for (int e = 0; e < 4; ++e) l[e] += gb[e];
        float mx = fmaxf(fmaxf(l[0], l[1]), fmaxf(l[2], l[3]));
#pragma unroll
        for (int e = 0; e < 4; ++e) { g[e] = expf(l[e] - mx); s += g[e]; }
#pragma unroll
        for (int e = 0; e < 4; ++e) g[e] /= s;
        int i1 = 0;
        for (int e = 1; e < 4; ++e) if (g[e] > g[i1]) i1 = e;   // first index wins ties
        int i2 = -1;
        for (int e = 0; e < 4; ++e) {
            if (e == i1) continue;
            if (i2 < 0 || g[e] > g[i2]) i2 = e;
        }
        float den = g[i1] + g[i2] + 1e-8f;
        sel_idx[b * 2 + 0] = i1;
        sel_idx[b * 2 + 1] = i2;
        sel_w[b * 2 + 0] = g[i1] / den;
        sel_w[b * 2 + 1] = g[i2] / den;
    }
}

// ---------------- per-expert conv + BN + GELU + gate-weight ----------------
// One instantiation per expert: compile-time K, D, exact-size LDS, fully
// static accumulator indexing (no scratch). Blocks whose (b,slot) did not
// select expert E exit immediately.
template <int E, int K, int D>
__global__ __launch_bounds__(256, 2)
void conv_expert_kernel(const float* __restrict__ x, const float* __restrict__ we,
                        const float* __restrict__ be, const float* __restrict__ bns,
                        const float* __restrict__ bnb, const float* __restrict__ bnm,
                        const float* __restrict__ bnv, const int* __restrict__ sel_idx,
                        const float* __restrict__ sel_w, float* __restrict__ out) {
    constexpr int K2 = K * K;
    constexpr int TS = 31 + (K - 1) * D;  // input tile span for 16 outputs @ stride 2
    __shared__ float xt[TS * 65];
    __shared__ float wt[K2 * 64];

    int bs = blockIdx.x;  // b*2 + slot (fastest dim -> expert mix across CUs)
    if (sel_idx[bs] != E) return;
    int b = bs >> 1, slot = bs & 1;
    float gwt = sel_w[bs];
    int tile = blockIdx.y;
    int oh0 = (tile >> 3) * 16, ow0 = (tile & 7) * 16;
    constexpr int PAD = (D * (K - 1)) / 2;
    int ih0 = oh0 * 2 - PAD, iw0 = ow0 * 2 - PAD;
    const float* xb = x + (size_t)b * CIN * HH * WW;

    int t = threadIdx.x, lane = t & 63, wv = t >> 6;
    int r = lane >> 2, cq = lane & 3;
    int co_l = t >> 2, kko = t & 3;
    const float* wbase = we + (size_t)co_l * (CIN * K2);

    float acc[64];
#pragma unroll
    for (int i = 0; i < 64; ++i) acc[i] = 0.f;

#pragma unroll 1
    for (int ci = 0; ci < CIN; ++ci) {
        __syncthreads();
        const float* xc = xb + (size_t)ci * (HH * WW);
        // stage input tile: wave handles rows wv, wv+4, ...; lane = column
#pragma unroll 1
        for (int row = wv; row < TS; row += 4) {
            if (lane < TS) {
                int ih = ih0 + row;
                int iw = iw0 + lane;
                float v = 0.f;
                if ((unsigned)ih < HH && (unsigned)iw < WW) v = xc[ih * WW + iw];
                xt[row * 65 + lane] = v;
            }
        }
        // stage weights as [k2][64co]
        const float* wc = wbase + ci * K2;
#pragma unroll 1
        for (int kk = kko; kk < K2; kk += 4) wt[kk * 64 + co_l] = wc[kk];
        __syncthreads();
#pragma unroll 1
        for (int kh = 0; kh < K; ++kh) {
            int xrb = (2 * r + kh * D) * 65;
#pragma unroll
            for (int kw = 0; kw < K; ++kw) {
                int xcb = cq * 8 + kw * D;
                float xv0 = xt[xrb + xcb + 0];
                float xv1 = xt[xrb + xcb + 2];
                float xv2 = xt[xrb + xcb + 4];
                float xv3 = xt[xrb + xcb + 6];
                const float4* wp =
                    reinterpret_cast<const float4*>(&wt[(kh * K + kw) * 64 + wv * 16]);
#pragma unroll
                for (int q = 0; q < 4; ++q) {
                    float4 w4 = wp[q];
                    float wf[4] = {w4.x, w4.y, w4.z, w4.w};
#pragma unroll
                    for (int cc = 0; cc < 4; ++cc) {
                        float* ap = acc + (q * 4 + cc) * 4;
                        ap[0] += wf[cc] * xv0;
                        ap[1] += wf[cc] * xv1;
                        ap[2] += wf[cc] * xv2;
                        ap[3] += wf[cc] * xv3;
                    }
                }
            }
        }
    }

    // epilogue: bias -> BN -> exact GELU -> gate weight  (FULLY unrolled: all
    // acc indices compile-time so acc stays in VGPRs)
    size_t obase = ((size_t)(b * 128 + slot * 64) * OHW + (oh0 + r)) * OHW + ow0 + cq * 4;
#pragma unroll
    for (int q = 0; q < 4; ++q) {
#pragma unroll
        for (int cc = 0; cc < 4; ++cc) {
            int co = wv * 16 + q * 4 + cc;
            float bias = be[co];
            float sc = bns[E * CE + co], bi = bnb[E * CE + co];
            float mn = bnm[E * CE + co], vr = bnv[E * CE + co];
            float inv = sc / sqrtf(vr + 1e-5f);
            float beta = bi - mn * inv;
            float4 o;
            float ys[4];
#pragma unroll
            for (int j = 0; j < 4; ++j) {
                float y = (acc[(q * 4 + cc) * 4 + j] + bias) * inv + beta;
                float g = 0.5f * y * (1.0f + erff(y * 0.70710678118654752f));
                ys[j] = g * gwt;
            }
            o.x = ys[0]; o.y = ys[1]; o.z = ys[2]; o.w = ys[3];
            *reinterpret_cast<float4*>(&out[obase + (size_t)co * (OHW * OHW)]) = o;
        }
    }
}

extern "C" void kernel_launch(void* const* d_in, const int* in_sizes, int n_in,
                              void* d_out, int out_size, void* d_ws, size_t ws_size,
                              hipStream_t stream) {
    const float* x   = (const float*)d_in[0];
    const float* w0  = (const float*)d_in[1];
    const float* b0  = (const float*)d_in[2];
    const float* w1  = (const float*)d_in[3];
    const float* b1  = (const float*)d_in[4];
    const float* w2  = (const float*)d_in[5];
    const float* b2  = (const float*)d_in[6];
    const float* w3  = (const float*)d_in[7];
    const float* b3  = (const float*)d_in[8];
    const float* bns = (const float*)d_in[9];
    const float* bnb = (const float*)d_in[10];
    const float* bnm = (const float*)d_in[11];
    const float* bnv = (const float*)d_in[12];
    const float* gw  = (const float*)d_in[13];
    const float* gb  = (const float*)d_in[14];
    float* out = (float*)d_out;

    float* pooled = (float*)d_ws;              // 1024 floats
    int* sel_idx  = ((int*)d_ws) + 1024;       // 32 ints
    float* sel_w  = ((float*)d_ws) + 1056;     // 32 floats

    pool_kernel<<<dim3(16 * CIN), 256, 0, stream>>>(x, pooled);
    gate_kernel<<<dim3(16), 64, 0, stream>>>(pooled, gw, gb, sel_idx, sel_w);

    dim3 grid(32, 64), blk(256);
    conv_expert_kernel<0, 3, 1><<<grid, blk, 0, stream>>>(x, w0, b0, bns, bnb, bnm, bnv,
                                                          sel_idx, sel_w, out);
    conv_expert_kernel<1, 5, 2><<<grid, blk, 0, stream>>>(x, w1, b1, bns, bnb, bnm, bnv,
                                                          sel_idx, sel_w, out);
    conv_expert_kernel<2, 7, 3><<<grid, blk, 0, stream>>>(x, w2, b2, bns, bnb, bnm, bnv,
                                                          sel_idx, sel_w, out);
    conv_expert_kernel<3, 9, 4><<<grid, blk, 0, stream>>>(x, w3, b3, bns, bnb, bnm, bnv,
                                                          sel_idx, sel_w, out);
}

// Round 3
// 3677.766 us; speedup vs baseline: 2.3431x; 2.3431x over previous
//
#include <hip/hip_runtime.h>
#include <hip/hip_bf16.h>
#include <math.h>

#define CIN 64
#define CE  64
#define HH  256
#define WW  256
#define OHW 128

typedef __attribute__((ext_vector_type(8))) short bf16x8;
typedef __attribute__((ext_vector_type(4))) float f32x4;

static __device__ __forceinline__ unsigned short f2bf(float f) {
    __hip_bfloat16 h = __float2bfloat16(f);
    return *reinterpret_cast<unsigned short*>(&h);
}

// ---------------- gate: global average pool ----------------
__global__ __launch_bounds__(256)
void pool_kernel(const float* __restrict__ x, float* __restrict__ pooled) {
    int bc = blockIdx.x;  // 0..B*CIN-1
    const float4* p = reinterpret_cast<const float4*>(x + (size_t)bc * (HH * WW));
    float s = 0.f;
    for (int i = threadIdx.x; i < (HH * WW) / 4; i += 256) {
        float4 v = p[i];
        s += (v.x + v.y) + (v.z + v.w);
    }
#pragma unroll
    for (int m = 32; m >= 1; m >>= 1) s += __shfl_xor(s, m, 64);
    __shared__ float red[4];
    int lane = threadIdx.x & 63, wv = threadIdx.x >> 6;
    if (lane == 0) red[wv] = s;
    __syncthreads();
    if (threadIdx.x == 0) {
        float t = (red[0] + red[1]) + (red[2] + red[3]);
        pooled[bc] = t * (1.0f / (HH * WW));
    }
}

// ---------------- gate: linear -> softmax -> top2 ----------------
__global__ __launch_bounds__(64)
void gate_kernel(const float* __restrict__ pooled, const float* __restrict__ gw,
                 const float* __restrict__ gb, int* __restrict__ sel_idx,
                 float* __restrict__ sel_w) {
    int b = blockIdx.x;
    int c = threadIdx.x;  // 0..63 == CIN
    float p = pooled[b * CIN + c];
    float l[4];
#pragma unroll
    for (int e = 0; e < 4; ++e) l[e] = p * gw[e * CIN + c];
#pragma unroll
    for (int m = 32; m >= 1; m >>= 1) {
#pragma unroll
        for (int e = 0; e < 4; ++e) l[e] += __shfl_xor(l[e], m, 64);
    }
    if (c == 0) {
        float g[4], s = 0.f;
#pragma unroll
        for (int e = 0; e < 4; ++e) l[e] += gb[e];
        float mx = fmaxf(fmaxf(l[0], l[1]), fmaxf(l[2], l[3]));
#pragma unroll
        for (int e = 0; e < 4; ++e) { g[e] = expf(l[e] - mx); s += g[e]; }
#pragma unroll
        for (int e = 0; e < 4; ++e) g[e] /= s;
        int i1 = 0;
        for (int e = 1; e < 4; ++e) if (g[e] > g[i1]) i1 = e;   // first index wins ties
        int i2 = -1;
        for (int e = 0; e < 4; ++e) {
            if (e == i1) continue;
            if (i2 < 0 || g[e] > g[i2]) i2 = e;
        }
        float den = g[i1] + g[i2] + 1e-8f;
        sel_idx[b * 2 + 0] = i1;
        sel_idx[b * 2 + 1] = i2;
        sel_w[b * 2 + 0] = g[i1] / den;
        sel_w[b * 2 + 1] = g[i2] / den;
    }
}

// ---------------- weight pre-pack: f32 (Ce,Cin,K,K) -> bf16 [cb8][grp][tap4][co64][ci8] ----
template <int K, int GE>
__global__ __launch_bounds__(256)
void wprep_kernel(const float* __restrict__ we, unsigned short* __restrict__ wout) {
    constexpr int K2 = K * K;
    int cb = blockIdx.x, g = blockIdx.y;
    int t = threadIdx.x;
    int tl = t >> 6, co = t & 63;
    int tap = g * 4 + tl;
    unsigned short vals[8];
#pragma unroll
    for (int j = 0; j < 8; ++j) {
        float v = 0.f;
        if (tap < K2) {
            int ci = cb * 8 + j;
            v = we[(size_t)(co * CIN + ci) * K2 + tap];
        }
        vals[j] = f2bf(v);
    }
    *reinterpret_cast<bf16x8*>(&wout[(size_t)(cb * GE + g) * 2048 + t * 8]) =
        *reinterpret_cast<const bf16x8*>(vals);
}

// ---------------- MFMA implicit-GEMM conv + BN + GELU + gate ----------------
// Block: 256 thr (4 waves) -> 64co x (16x16) output patch.
// K per MFMA = 4 taps (lane hi-group) x 8 ci. x tile in LDS, bf16,
// [row][col-parity][slot][ci8] so stride-2 reads are slot-consecutive.
template <int E, int K, int D, int GE>
__global__ __launch_bounds__(256, 2)
void conv_mfma_kernel(const float* __restrict__ x, const unsigned short* __restrict__ wq,
                      const float* __restrict__ be, const float* __restrict__ bns,
                      const float* __restrict__ bnb, const float* __restrict__ bnm,
                      const float* __restrict__ bnv, const int* __restrict__ sel_idx,
                      const float* __restrict__ sel_w, float* __restrict__ out) {
    constexpr int K2 = K * K;
    constexpr int TS = 31 + (K - 1) * D;       // input span for 16 outputs @ stride 2
    constexpr int SLOTS = (TS + 1) / 2;
    constexpr int HPW = SLOTS * 8;             // half-plane pitch (shorts)
    constexpr int PITCHW = 2 * HPW;            // row pitch (shorts)
    __shared__ __align__(16) unsigned short xt[TS * PITCHW];

    int bs = blockIdx.x;
    if (sel_idx[bs] != E) return;
    int b = bs >> 1, slot = bs & 1;
    float gwt = sel_w[bs];
    int tile = blockIdx.y;
    int oh0 = (tile >> 3) * 16, ow0 = (tile & 7) * 16;
    constexpr int PAD = (D * (K - 1)) / 2;
    int ih0 = oh0 * 2 - PAD, iw0 = ow0 * 2 - PAD;
    const float* xb = x + (size_t)b * CIN * HH * WW;

    int t = threadIdx.x, lane = t & 63, wv = t >> 6;
    int p = lane & 15, hi = lane >> 4;

    f32x4 acc[4][4];  // [oh j][co-tile]
#pragma unroll
    for (int j = 0; j < 4; ++j)
#pragma unroll
        for (int ct = 0; ct < 4; ++ct) acc[j][ct] = (f32x4){0.f, 0.f, 0.f, 0.f};

#pragma unroll 1
    for (int cb = 0; cb < 8; ++cb) {
        __syncthreads();
        // ---- stage x tile (8 ci) into LDS, f32 -> bf16, parity-split cols ----
#pragma unroll 1
        for (int ir = wv; ir < TS; ir += 4) {
            if (lane < TS) {
                int ih = ih0 + ir, iw = iw0 + lane;
                unsigned short u[8];
                bool inb = ((unsigned)ih < HH) && ((unsigned)iw < WW);
#pragma unroll
                for (int j = 0; j < 8; ++j) {
                    float v = 0.f;
                    if (inb) v = xb[(size_t)(cb * 8 + j) * (HH * WW) + ih * WW + iw];
                    u[j] = f2bf(v);
                }
                int dst = ir * PITCHW + (lane & 1) * HPW + (lane >> 1) * 8;
                *reinterpret_cast<bf16x8*>(&xt[dst]) = *reinterpret_cast<const bf16x8*>(u);
            }
        }
        __syncthreads();
        // ---- K loop over tap groups ----
        const unsigned short* wcb = wq + (size_t)cb * GE * 2048;
#pragma unroll 1
        for (int g = 0; g < GE; ++g) {
            int tap = g * 4 + hi;
            int tapc = tap < K2 ? tap : K2 - 1;     // dummy taps have zero weights
            int kh = tapc / K, kw = tapc % K;
            const unsigned short* wg = wcb + g * 2048 + hi * 512;
            bf16x8 a0 = *reinterpret_cast<const bf16x8*>(wg + p * 8);
            bf16x8 a1 = *reinterpret_cast<const bf16x8*>(wg + 128 + p * 8);
            bf16x8 a2 = *reinterpret_cast<const bf16x8*>(wg + 256 + p * 8);
            bf16x8 a3 = *reinterpret_cast<const bf16x8*>(wg + 384 + p * 8);
            int ic = 2 * p + kw * D;
            int bbase = (ic & 1) * HPW + (ic >> 1) * 8;
            int irb = kh * D + wv * 8;
#pragma unroll
            for (int j = 0; j < 4; ++j) {
                bf16x8 bf = *reinterpret_cast<const bf16x8*>(&xt[(irb + 2 * j) * PITCHW + bbase]);
                acc[j][0] = __builtin_amdgcn_mfma_f32_16x16x32_bf16(a0, bf, acc[j][0], 0, 0, 0);
                acc[j][1] = __builtin_amdgcn_mfma_f32_16x16x32_bf16(a1, bf, acc[j][1], 0, 0, 0);
                acc[j][2] = __builtin_amdgcn_mfma_f32_16x16x32_bf16(a2, bf, acc[j][2], 0, 0, 0);
                acc[j][3] = __builtin_amdgcn_mfma_f32_16x16x32_bf16(a3, bf, acc[j][3], 0, 0, 0);
            }
        }
    }

    // ---- epilogue: BN(+bias) -> exact GELU -> gate weight -> store ----
    float* ob = out + (size_t)(b * 128 + slot * 64) * (OHW * OHW);
#pragma unroll
    for (int ct = 0; ct < 4; ++ct) {
#pragma unroll
        for (int reg = 0; reg < 4; ++reg) {
            int co = ct * 16 + hi * 4 + reg;
            float bias = be[co];
            float sc = bns[E * CE + co], bi = bnb[E * CE + co];
            float mn = bnm[E * CE + co], vr = bnv[E * CE + co];
            float inv = sc * rsqrtf(vr + 1e-5f);
            float beta = bi - mn * inv + bias * inv;
#pragma unroll
            for (int j = 0; j < 4; ++j) {
                float y = acc[j][ct][reg] * inv + beta;
                float gl = 0.5f * y * (1.0f + erff(y * 0.70710678118654752f));
                int oh = oh0 + wv * 4 + j, ow = ow0 + p;
                ob[(size_t)co * (OHW * OHW) + oh * OHW + ow] = gl * gwt;
            }
        }
    }
}

extern "C" void kernel_launch(void* const* d_in, const int* in_sizes, int n_in,
                              void* d_out, int out_size, void* d_ws, size_t ws_size,
                              hipStream_t stream) {
    const float* x   = (const float*)d_in[0];
    const float* w0  = (const float*)d_in[1];
    const float* b0  = (const float*)d_in[2];
    const float* w1  = (const float*)d_in[3];
    const float* b1  = (const float*)d_in[4];
    const float* w2  = (const float*)d_in[5];
    const float* b2  = (const float*)d_in[6];
    const float* w3  = (const float*)d_in[7];
    const float* b3  = (const float*)d_in[8];
    const float* bns = (const float*)d_in[9];
    const float* bnb = (const float*)d_in[10];
    const float* bnm = (const float*)d_in[11];
    const float* bnv = (const float*)d_in[12];
    const float* gw  = (const float*)d_in[13];
    const float* gb  = (const float*)d_in[14];
    float* out = (float*)d_out;

    char* ws = (char*)d_ws;
    float* pooled = (float*)ws;                         // 4096 B
    int* sel_idx  = (int*)(ws + 4096);                  // 128 B
    float* sel_w  = (float*)(ws + 4224);                // 128 B
    unsigned short* wq = (unsigned short*)(ws + 4352);  // bf16 packed weights
    // per-expert packed sizes (shorts): 8*GE*2048
    unsigned short* wq0 = wq;             // GE=3
    unsigned short* wq1 = wq + 49152;     // GE=7
    unsigned short* wq2 = wq + 163840;    // GE=13
    unsigned short* wq3 = wq + 376832;    // GE=21

    pool_kernel<<<dim3(16 * CIN), 256, 0, stream>>>(x, pooled);
    gate_kernel<<<dim3(16), 64, 0, stream>>>(pooled, gw, gb, sel_idx, sel_w);

    wprep_kernel<3, 3><<<dim3(8, 3), 256, 0, stream>>>(w0, wq0);
    wprep_kernel<5, 7><<<dim3(8, 7), 256, 0, stream>>>(w1, wq1);
    wprep_kernel<7, 13><<<dim3(8, 13), 256, 0, stream>>>(w2, wq2);
    wprep_kernel<9, 21><<<dim3(8, 21), 256, 0, stream>>>(w3, wq3);

    dim3 grid(32, 64), blk(256);
    conv_mfma_kernel<0, 3, 1, 3><<<grid, blk, 0, stream>>>(x, wq0, b0, bns, bnb, bnm, bnv,
                                                           sel_idx, sel_w, out);
    conv_mfma_kernel<1, 5, 2, 7><<<grid, blk, 0, stream>>>(x, wq1, b1, bns, bnb, bnm, bnv,
                                                           sel_idx, sel_w, out);
    conv_mfma_kernel<2, 7, 3, 13><<<grid, blk, 0, stream>>>(x, wq2, b2, bns, bnb, bnm, bnv,
                                                            sel_idx, sel_w, out);
    conv_mfma_kernel<3, 9, 4, 21><<<grid, blk, 0, stream>>>(x, wq3, b3, bns, bnb, bnm, bnv,
                                                            sel_idx, sel_w, out);
}

// Round 4
// 537.107 us; speedup vs baseline: 16.0444x; 6.8474x over previous
//
#include <hip/hip_runtime.h>
#include <hip/hip_bf16.h>
#include <math.h>

#define CIN 64
#define CE  64
#define HH  256
#define WW  256
#define OHW 128

typedef __attribute__((ext_vector_type(8))) short bf16x8;
typedef __attribute__((ext_vector_type(4))) float f32x4;

static __device__ __forceinline__ unsigned short f2bf(float f) {
    __hip_bfloat16 h = __float2bfloat16(f);
    return *reinterpret_cast<unsigned short*>(&h);
}

// ---------------- gate: global average pool ----------------
__global__ __launch_bounds__(256)
void pool_kernel(const float* __restrict__ x, float* __restrict__ pooled) {
    int bc = blockIdx.x;  // 0..B*CIN-1
    const float4* p = reinterpret_cast<const float4*>(x + (size_t)bc * (HH * WW));
    float s = 0.f;
    for (int i = threadIdx.x; i < (HH * WW) / 4; i += 256) {
        float4 v = p[i];
        s += (v.x + v.y) + (v.z + v.w);
    }
#pragma unroll
    for (int m = 32; m >= 1; m >>= 1) s += __shfl_xor(s, m, 64);
    __shared__ float red[4];
    int lane = threadIdx.x & 63, wv = threadIdx.x >> 6;
    if (lane == 0) red[wv] = s;
    __syncthreads();
    if (threadIdx.x == 0) {
        float t = (red[0] + red[1]) + (red[2] + red[3]);
        pooled[bc] = t * (1.0f / (HH * WW));
    }
}

// ---------------- gate: linear -> softmax -> top2 ----------------
__global__ __launch_bounds__(64)
void gate_kernel(const float* __restrict__ pooled, const float* __restrict__ gw,
                 const float* __restrict__ gb, int* __restrict__ sel_idx,
                 float* __restrict__ sel_w) {
    int b = blockIdx.x;
    int c = threadIdx.x;  // 0..63 == CIN
    float p = pooled[b * CIN + c];
    float l[4];
#pragma unroll
    for (int e = 0; e < 4; ++e) l[e] = p * gw[e * CIN + c];
#pragma unroll
    for (int m = 32; m >= 1; m >>= 1) {
#pragma unroll
        for (int e = 0; e < 4; ++e) l[e] += __shfl_xor(l[e], m, 64);
    }
    if (c == 0) {
        float g[4], s = 0.f;
#pragma unroll
        for (int e = 0; e < 4; ++e) l[e] += gb[e];
        float mx = fmaxf(fmaxf(l[0], l[1]), fmaxf(l[2], l[3]));
#pragma unroll
        for (int e = 0; e < 4; ++e) { g[e] = expf(l[e] - mx); s += g[e]; }
#pragma unroll
        for (int e = 0; e < 4; ++e) g[e] /= s;
        int i1 = 0;
        for (int e = 1; e < 4; ++e) if (g[e] > g[i1]) i1 = e;   // first index wins ties
        int i2 = -1;
        for (int e = 0; e < 4; ++e) {
            if (e == i1) continue;
            if (i2 < 0 || g[e] > g[i2]) i2 = e;
        }
        float den = g[i1] + g[i2] + 1e-8f;
        sel_idx[b * 2 + 0] = i1;
        sel_idx[b * 2 + 1] = i2;
        sel_w[b * 2 + 0] = g[i1] / den;
        sel_w[b * 2 + 1] = g[i2] / den;
    }
}

// ---------------- weight pre-pack: f32 (Ce,Cin,K,K) -> bf16 [cb8][grp][tap4][co64][ci8] ----
template <int K, int GE>
__global__ __launch_bounds__(256)
void wprep_kernel(const float* __restrict__ we, unsigned short* __restrict__ wout) {
    constexpr int K2 = K * K;
    int cb = blockIdx.x, g = blockIdx.y;
    int t = threadIdx.x;
    int tl = t >> 6, co = t & 63;
    int tap = g * 4 + tl;
    unsigned short vals[8];
#pragma unroll
    for (int j = 0; j < 8; ++j) {
        float v = 0.f;
        if (tap < K2) {
            int ci = cb * 8 + j;
            v = we[(size_t)(co * CIN + ci) * K2 + tap];
        }
        vals[j] = f2bf(v);
    }
    *reinterpret_cast<bf16x8*>(&wout[(size_t)(cb * GE + g) * 2048 + t * 8]) =
        *reinterpret_cast<const bf16x8*>(vals);
}

// ---------------- staging helpers ----------------
// Full lattice (odd dilation): parity-split layout [row][parity][slot][ci8]
template <int TS, int HPW>
__device__ __forceinline__ void stage_full(const float* __restrict__ xb, int cb,
                                           int ih0, int iw0,
                                           unsigned short* __restrict__ xt,
                                           int lane, int wv) {
    constexpr int PITCH = 2 * HPW;
    if (lane < TS) {
        int iw = iw0 + lane;
        int iwc = min(max(iw, 0), WW - 1);
        bool cok = (unsigned)iw < (unsigned)WW;
        int dst0 = (lane & 1) * HPW + (lane >> 1) * 8;
#pragma unroll 2
        for (int ir = wv; ir < TS; ir += 4) {
            int ih = ih0 + ir;
            int ihc = min(max(ih, 0), HH - 1);
            bool ok = cok && ((unsigned)ih < (unsigned)HH);
            const float* src = xb + ihc * WW + iwc;
            unsigned short u[8];
#pragma unroll
            for (int j = 0; j < 8; ++j) {
                float v = src[(size_t)(cb * 8 + j) * (HH * WW)];
                u[j] = f2bf(ok ? v : 0.f);
            }
            *reinterpret_cast<bf16x8*>(&xt[ir * PITCH + dst0]) =
                *reinterpret_cast<const bf16x8*>(u);
        }
    }
}

// Even lattice (even dilation + even pad): only even rows/cols ever read.
// Layout [er][ec][ci8], NRC x NRC.
template <int NRC>
__device__ __forceinline__ void stage_even(const float* __restrict__ xb, int cb,
                                           int ih0, int iw0,
                                           unsigned short* __restrict__ xt,
                                           int lane, int wv) {
    if (lane < NRC) {
        int iw = iw0 + 2 * lane;
        int iwc = min(max(iw, 0), WW - 1);
        bool cok = (unsigned)iw < (unsigned)WW;
#pragma unroll 2
        for (int er = wv; er < NRC; er += 4) {
            int ih = ih0 + 2 * er;
            int ihc = min(max(ih, 0), HH - 1);
            bool ok = cok && ((unsigned)ih < (unsigned)HH);
            const float* src = xb + ihc * WW + iwc;
            unsigned short u[8];
#pragma unroll
            for (int j = 0; j < 8; ++j) {
                float v = src[(size_t)(cb * 8 + j) * (HH * WW)];
                u[j] = f2bf(ok ? v : 0.f);
            }
            *reinterpret_cast<bf16x8*>(&xt[(er * NRC + lane) * 8]) =
                *reinterpret_cast<const bf16x8*>(u);
        }
    }
}

// ---------------- conv body (compile-time expert geometry) ----------------
template <int K, int D, int GE, bool EVEN>
__device__ __forceinline__ void conv_body(const float* __restrict__ xb,
                                          const unsigned short* __restrict__ wq,
                                          unsigned short* __restrict__ xt,
                                          f32x4 acc[4][4],
                                          int ih0, int iw0, int lane, int wv) {
    constexpr int K2 = K * K;
    constexpr int TS = 31 + (K - 1) * D;
    constexpr int SLOTS = (TS + 1) / 2;
    constexpr int HPW = SLOTS * 8;
    constexpr int PITCH = 2 * HPW;
    constexpr int NRC = (TS + 1) / 2;  // even-lattice rows/cols
    int p = lane & 15, hi = lane >> 4;

#pragma unroll 1
    for (int cb = 0; cb < 8; ++cb) {
        __syncthreads();
        if (EVEN) stage_even<NRC>(xb, cb, ih0, iw0, xt, lane, wv);
        else      stage_full<TS, HPW>(xb, cb, ih0, iw0, xt, lane, wv);
        __syncthreads();
        const unsigned short* wcb = wq + (size_t)cb * GE * 2048;
#pragma unroll 2
        for (int g = 0; g < GE; ++g) {
            int tap = g * 4 + hi;
            int tapc = tap < K2 ? tap : K2 - 1;  // dummy taps carry zero weights
            int kh = tapc / K, kw = tapc % K;
            const unsigned short* wg = wcb + g * 2048 + hi * 512;
            bf16x8 a0 = *reinterpret_cast<const bf16x8*>(wg + p * 8);
            bf16x8 a1 = *reinterpret_cast<const bf16x8*>(wg + 128 + p * 8);
            bf16x8 a2 = *reinterpret_cast<const bf16x8*>(wg + 256 + p * 8);
            bf16x8 a3 = *reinterpret_cast<const bf16x8*>(wg + 384 + p * 8);
            if (EVEN) {
                constexpr int DH = D / 2;
                int ec = p + DH * kw;
                int erb = wv * 4 + DH * kh;
#pragma unroll
                for (int j = 0; j < 4; ++j) {
                    const bf16x8 bf = *reinterpret_cast<const bf16x8*>(
                        &xt[((erb + j) * NRC + ec) * 8]);
                    acc[j][0] = __builtin_amdgcn_mfma_f32_16x16x32_bf16(a0, bf, acc[j][0], 0, 0, 0);
                    acc[j][1] = __builtin_amdgcn_mfma_f32_16x16x32_bf16(a1, bf, acc[j][1], 0, 0, 0);
                    acc[j][2] = __builtin_amdgcn_mfma_f32_16x16x32_bf16(a2, bf, acc[j][2], 0, 0, 0);
                    acc[j][3] = __builtin_amdgcn_mfma_f32_16x16x32_bf16(a3, bf, acc[j][3], 0, 0, 0);
                }
            } else {
                int ic = 2 * p + D * kw;
                int bbase = (ic & 1) * HPW + (ic >> 1) * 8;
                int irb = D * kh + wv * 8;
#pragma unroll
                for (int j = 0; j < 4; ++j) {
                    const bf16x8 bf = *reinterpret_cast<const bf16x8*>(
                        &xt[(irb + 2 * j) * PITCH + bbase]);
                    acc[j][0] = __builtin_amdgcn_mfma_f32_16x16x32_bf16(a0, bf, acc[j][0], 0, 0, 0);
                    acc[j][1] = __builtin_amdgcn_mfma_f32_16x16x32_bf16(a1, bf, acc[j][1], 0, 0, 0);
                    acc[j][2] = __builtin_amdgcn_mfma_f32_16x16x32_bf16(a2, bf, acc[j][2], 0, 0, 0);
                    acc[j][3] = __builtin_amdgcn_mfma_f32_16x16x32_bf16(a3, bf, acc[j][3], 0, 0, 0);
                }
            }
        }
    }
}

// ---------------- unified MoE conv + BN + GELU + gate ----------------
__global__ __launch_bounds__(256, 4)
void conv_moe_kernel(const float* __restrict__ x,
                     const unsigned short* __restrict__ wq0,
                     const unsigned short* __restrict__ wq1,
                     const unsigned short* __restrict__ wq2,
                     const unsigned short* __restrict__ wq3,
                     const float* __restrict__ b0_, const float* __restrict__ b1_,
                     const float* __restrict__ b2_, const float* __restrict__ b3_,
                     const float* __restrict__ bns, const float* __restrict__ bnb,
                     const float* __restrict__ bnm, const float* __restrict__ bnv,
                     const int* __restrict__ sel_idx, const float* __restrict__ sel_w,
                     float* __restrict__ out) {
    __shared__ __align__(16) unsigned short xt[19600];  // K=7 worst case: 49*400

    int bs = blockIdx.x;  // b*2 + slot
    int b = bs >> 1, slot = bs & 1;
    int e = sel_idx[bs];
    float gwt = sel_w[bs];
    int tile = blockIdx.y;
    int oh0 = (tile >> 3) * 16, ow0 = (tile & 7) * 16;
    const float* xb = x + (size_t)b * CIN * HH * WW;
    int lane = threadIdx.x & 63, wv = threadIdx.x >> 6;
    int p = lane & 15, hi = lane >> 4;

    f32x4 acc[4][4];
#pragma unroll
    for (int j = 0; j < 4; ++j)
#pragma unroll
        for (int ct = 0; ct < 4; ++ct) acc[j][ct] = (f32x4){0.f, 0.f, 0.f, 0.f};

    switch (e) {
        case 0:
            conv_body<3, 1, 3, false>(xb, wq0, xt, acc, oh0 * 2 - 1, ow0 * 2 - 1, lane, wv);
            break;
        case 1:
            conv_body<5, 2, 7, true>(xb, wq1, xt, acc, oh0 * 2 - 4, ow0 * 2 - 4, lane, wv);
            break;
        case 2:
            conv_body<7, 3, 13, false>(xb, wq2, xt, acc, oh0 * 2 - 9, ow0 * 2 - 9, lane, wv);
            break;
        default:
            conv_body<9, 4, 21, true>(xb, wq3, xt, acc, oh0 * 2 - 16, ow0 * 2 - 16, lane, wv);
            break;
    }

    const float* be = (e == 0) ? b0_ : (e == 1) ? b1_ : (e == 2) ? b2_ : b3_;
    float* ob = out + (size_t)(b * 128 + slot * 64) * (OHW * OHW);
#pragma unroll
    for (int ct = 0; ct < 4; ++ct) {
#pragma unroll
        for (int reg = 0; reg < 4; ++reg) {
            int co = ct * 16 + hi * 4 + reg;
            float bias = be[co];
            float sc = bns[e * CE + co], bi = bnb[e * CE + co];
            float mn = bnm[e * CE + co], vr = bnv[e * CE + co];
            float inv = sc * rsqrtf(vr + 1e-5f);
            float beta = bi - mn * inv + bias * inv;
#pragma unroll
            for (int j = 0; j < 4; ++j) {
                float y = acc[j][ct][reg] * inv + beta;
                float gl = 0.5f * y * (1.0f + erff(y * 0.70710678118654752f));
                int oh = oh0 + wv * 4 + j, ow = ow0 + p;
                ob[(size_t)co * (OHW * OHW) + oh * OHW + ow] = gl * gwt;
            }
        }
    }
}

extern "C" void kernel_launch(void* const* d_in, const int* in_sizes, int n_in,
                              void* d_out, int out_size, void* d_ws, size_t ws_size,
                              hipStream_t stream) {
    const float* x   = (const float*)d_in[0];
    const float* w0  = (const float*)d_in[1];
    const float* b0  = (const float*)d_in[2];
    const float* w1  = (const float*)d_in[3];
    const float* b1  = (const float*)d_in[4];
    const float* w2  = (const float*)d_in[5];
    const float* b2  = (const float*)d_in[6];
    const float* w3  = (const float*)d_in[7];
    const float* b3  = (const float*)d_in[8];
    const float* bns = (const float*)d_in[9];
    const float* bnb = (const float*)d_in[10];
    const float* bnm = (const float*)d_in[11];
    const float* bnv = (const float*)d_in[12];
    const float* gw  = (const float*)d_in[13];
    const float* gb  = (const float*)d_in[14];
    float* out = (float*)d_out;

    char* ws = (char*)d_ws;
    float* pooled = (float*)ws;                         // 4096 B
    int* sel_idx  = (int*)(ws + 4096);                  // 128 B
    float* sel_w  = (float*)(ws + 4224);                // 128 B
    unsigned short* wq = (unsigned short*)(ws + 4352);  // bf16 packed weights
    unsigned short* wq0 = wq;             // GE=3
    unsigned short* wq1 = wq + 49152;     // GE=7
    unsigned short* wq2 = wq + 163840;    // GE=13
    unsigned short* wq3 = wq + 376832;    // GE=21

    pool_kernel<<<dim3(16 * CIN), 256, 0, stream>>>(x, pooled);
    gate_kernel<<<dim3(16), 64, 0, stream>>>(pooled, gw, gb, sel_idx, sel_w);

    wprep_kernel<3, 3><<<dim3(8, 3), 256, 0, stream>>>(w0, wq0);
    wprep_kernel<5, 7><<<dim3(8, 7), 256, 0, stream>>>(w1, wq1);
    wprep_kernel<7, 13><<<dim3(8, 13), 256, 0, stream>>>(w2, wq2);
    wprep_kernel<9, 21><<<dim3(8, 21), 256, 0, stream>>>(w3, wq3);

    conv_moe_kernel<<<dim3(32, 64), 256, 0, stream>>>(
        x, wq0, wq1, wq2, wq3, b0, b1, b2, b3, bns, bnb, bnm, bnv, sel_idx, sel_w, out);
}

// Round 5
// 325.304 us; speedup vs baseline: 26.4908x; 1.6511x over previous
//
#include <hip/hip_runtime.h>
#include <hip/hip_bf16.h>
#include <math.h>

#define CIN 64
#define CE  64
#define HH  256
#define WW  256
#define OHW 128

typedef __attribute__((ext_vector_type(8))) short bf16x8;
typedef __attribute__((ext_vector_type(4))) float f32x4;

static __device__ __forceinline__ unsigned short f2bf(float f) {
    __hip_bfloat16 h = __float2bfloat16(f);
    return *reinterpret_cast<unsigned short*>(&h);
}

// ---------------- fused: global average pool partials + x -> bf16 NHWC8 ----------------
// grid (128, 8): blockIdx.x = b*8+cb (8-channel group), blockIdx.y = 32-row chunk.
// Writes xbf[(b*8+cb)][h][w][ci8] (bf16) when PRE, and per-(b,cb,rowchunk) pool partials.
template <bool PRE>
__global__ __launch_bounds__(256)
void poolcvt_kernel(const float* __restrict__ x, unsigned short* __restrict__ xbf,
                    float* __restrict__ partial) {
    int blk = blockIdx.x;  // b*8+cb
    int rc = blockIdx.y;   // 0..7
    int lane = threadIdx.x & 63, wv = threadIdx.x >> 6;
    int c0 = lane * 4;
    const float* xb = x + (size_t)blk * 8 * (HH * WW);
    float s[8];
#pragma unroll
    for (int j = 0; j < 8; ++j) s[j] = 0.f;
#pragma unroll 1
    for (int rr = wv; rr < 32; rr += 4) {
        int h = rc * 32 + rr;
        float4 v[8];
#pragma unroll
        for (int j = 0; j < 8; ++j)
            v[j] = *reinterpret_cast<const float4*>(xb + (size_t)j * (HH * WW) + h * WW + c0);
#pragma unroll
        for (int j = 0; j < 8; ++j) s[j] += (v[j].x + v[j].y) + (v[j].z + v[j].w);
        if (PRE) {
            size_t o16 = ((size_t)blk * HH + h) * WW + c0;  // in 8-short units
            unsigned short u[4][8];
#pragma unroll
            for (int j = 0; j < 8; ++j) {
                u[0][j] = f2bf(v[j].x);
                u[1][j] = f2bf(v[j].y);
                u[2][j] = f2bf(v[j].z);
                u[3][j] = f2bf(v[j].w);
            }
#pragma unroll
            for (int cc = 0; cc < 4; ++cc)
                *reinterpret_cast<bf16x8*>(xbf + (o16 + cc) * 8) =
                    *reinterpret_cast<const bf16x8*>(u[cc]);
        }
    }
#pragma unroll
    for (int j = 0; j < 8; ++j) {
#pragma unroll
        for (int m = 32; m >= 1; m >>= 1) s[j] += __shfl_xor(s[j], m, 64);
    }
    __shared__ float red[4][8];
    if (lane == 0) {
#pragma unroll
        for (int j = 0; j < 8; ++j) red[wv][j] = s[j];
    }
    __syncthreads();
    if (threadIdx.x < 8) {
        int j = threadIdx.x;
        float t = (red[0][j] + red[1][j]) + (red[2][j] + red[3][j]);
        partial[(blk * 8 + rc) * 8 + j] = t;  // [b][cb][rc][ci8]
    }
}

// ---------------- gate: (sum partials) -> linear -> softmax -> top2 ----------------
__global__ __launch_bounds__(64)
void gate_kernel(const float* __restrict__ partial, const float* __restrict__ gw,
                 const float* __restrict__ gb, int* __restrict__ sel_idx,
                 float* __restrict__ sel_w) {
    int b = blockIdx.x;
    int c = threadIdx.x;  // 0..63 == CIN
    float p = 0.f;
#pragma unroll
    for (int rc = 0; rc < 8; ++rc)
        p += partial[(((b * 8 + (c >> 3)) * 8) + rc) * 8 + (c & 7)];
    p *= (1.0f / (HH * WW));
    float l[4];
#pragma unroll
    for (int e = 0; e < 4; ++e) l[e] = p * gw[e * CIN + c];
#pragma unroll
    for (int m = 32; m >= 1; m >>= 1) {
#pragma unroll
        for (int e = 0; e < 4; ++e) l[e] += __shfl_xor(l[e], m, 64);
    }
    if (c == 0) {
        float g[4], s = 0.f;
#pragma unroll
        for (int e = 0; e < 4; ++e) l[e] += gb[e];
        float mx = fmaxf(fmaxf(l[0], l[1]), fmaxf(l[2], l[3]));
#pragma unroll
        for (int e = 0; e < 4; ++e) { g[e] = expf(l[e] - mx); s += g[e]; }
#pragma unroll
        for (int e = 0; e < 4; ++e) g[e] /= s;
        int i1 = 0;
        for (int e = 1; e < 4; ++e) if (g[e] > g[i1]) i1 = e;   // first index wins ties
        int i2 = -1;
        for (int e = 0; e < 4; ++e) {
            if (e == i1) continue;
            if (i2 < 0 || g[e] > g[i2]) i2 = e;
        }
        float den = g[i1] + g[i2] + 1e-8f;
        sel_idx[b * 2 + 0] = i1;
        sel_idx[b * 2 + 1] = i2;
        sel_w[b * 2 + 0] = g[i1] / den;
        sel_w[b * 2 + 1] = g[i2] / den;
    }
}

// ---------------- LPT order: heavy experts (large GE) dispatch first ----------------
__global__ void order_kernel(const int* __restrict__ sel_idx, int* __restrict__ ord) {
    if (threadIdx.x == 0) {
        int pos = 0;
        const int pri[4] = {3, 2, 1, 0};  // GE: 21, 13, 7, 3
        for (int pi = 0; pi < 4; ++pi)
            for (int bs = 0; bs < 32; ++bs)
                if (sel_idx[bs] == pri[pi]) ord[pos++] = bs;
    }
}

// ---------------- weight pre-pack: f32 (Ce,Cin,K,K) -> bf16 [cb8][grp][tap4][co64][ci8] ----
template <int K, int GE>
__global__ __launch_bounds__(256)
void wprep_kernel(const float* __restrict__ we, unsigned short* __restrict__ wout) {
    constexpr int K2 = K * K;
    int cb = blockIdx.x, g = blockIdx.y;
    int t = threadIdx.x;
    int tl = t >> 6, co = t & 63;
    int tap = g * 4 + tl;
    unsigned short vals[8];
#pragma unroll
    for (int j = 0; j < 8; ++j) {
        float v = 0.f;
        if (tap < K2) {
            int ci = cb * 8 + j;
            v = we[(size_t)(co * CIN + ci) * K2 + tap];
        }
        vals[j] = f2bf(v);
    }
    *reinterpret_cast<bf16x8*>(&wout[(size_t)(cb * GE + g) * 2048 + t * 8]) =
        *reinterpret_cast<const bf16x8*>(vals);
}

// ---------------- staging helpers ----------------
// Full lattice (odd dilation): parity-split layout [row][parity][slot][ci8]
template <int TS, int HPW, bool PRE>
__device__ __forceinline__ void stage_full(const float* __restrict__ xc8,
                                           const unsigned short* __restrict__ xbb,
                                           int ih0, int iw0,
                                           unsigned short* __restrict__ xt,
                                           int lane, int wv) {
    constexpr int PITCH = 2 * HPW;
    if (lane < TS) {
        int iw = iw0 + lane;
        int iwc = min(max(iw, 0), WW - 1);
        bool cok = (unsigned)iw < (unsigned)WW;
        int dst0 = (lane & 1) * HPW + (lane >> 1) * 8;
        if (PRE) {
#pragma unroll 4
            for (int ir = wv; ir < TS; ir += 4) {
                int ih = ih0 + ir;
                int ihc = min(max(ih, 0), HH - 1);
                bool ok = cok && ((unsigned)ih < (unsigned)HH);
                bf16x8 v = *reinterpret_cast<const bf16x8*>(xbb + ((size_t)ihc * WW + iwc) * 8);
                if (!ok) v = (bf16x8)(short)0;
                *reinterpret_cast<bf16x8*>(&xt[ir * PITCH + dst0]) = v;
            }
        } else {
#pragma unroll 2
            for (int ir = wv; ir < TS; ir += 4) {
                int ih = ih0 + ir;
                int ihc = min(max(ih, 0), HH - 1);
                bool ok = cok && ((unsigned)ih < (unsigned)HH);
                const float* src = xc8 + ihc * WW + iwc;
                unsigned short u[8];
#pragma unroll
                for (int j = 0; j < 8; ++j) {
                    float v = src[(size_t)j * (HH * WW)];
                    u[j] = f2bf(ok ? v : 0.f);
                }
                *reinterpret_cast<bf16x8*>(&xt[ir * PITCH + dst0]) =
                    *reinterpret_cast<const bf16x8*>(u);
            }
        }
    }
}

// Even lattice (even dilation + even pad): only even rows/cols ever read. [er][ec][ci8]
template <int NRC, bool PRE>
__device__ __forceinline__ void stage_even(const float* __restrict__ xc8,
                                           const unsigned short* __restrict__ xbb,
                                           int ih0, int iw0,
                                           unsigned short* __restrict__ xt,
                                           int lane, int wv) {
    if (lane < NRC) {
        int iw = iw0 + 2 * lane;
        int iwc = min(max(iw, 0), WW - 1);
        bool cok = (unsigned)iw < (unsigned)WW;
        if (PRE) {
#pragma unroll 4
            for (int er = wv; er < NRC; er += 4) {
                int ih = ih0 + 2 * er;
                int ihc = min(max(ih, 0), HH - 1);
                bool ok = cok && ((unsigned)ih < (unsigned)HH);
                bf16x8 v = *reinterpret_cast<const bf16x8*>(xbb + ((size_t)ihc * WW + iwc) * 8);
                if (!ok) v = (bf16x8)(short)0;
                *reinterpret_cast<bf16x8*>(&xt[(er * NRC + lane) * 8]) = v;
            }
        } else {
#pragma unroll 2
            for (int er = wv; er < NRC; er += 4) {
                int ih = ih0 + 2 * er;
                int ihc = min(max(ih, 0), HH - 1);
                bool ok = cok && ((unsigned)ih < (unsigned)HH);
                const float* src = xc8 + ihc * WW + iwc;
                unsigned short u[8];
#pragma unroll
                for (int j = 0; j < 8; ++j) {
                    float v = src[(size_t)j * (HH * WW)];
                    u[j] = f2bf(ok ? v : 0.f);
                }
                *reinterpret_cast<bf16x8*>(&xt[(er * NRC + lane) * 8]) =
                    *reinterpret_cast<const bf16x8*>(u);
            }
        }
    }
}

// ---------------- conv body (compile-time expert geometry) ----------------
template <int K, int D, int GE, bool EVEN, bool PRE>
__device__ __forceinline__ void conv_body(const float* __restrict__ xb,
                                          const unsigned short* __restrict__ xbf_b,
                                          const unsigned short* __restrict__ wq,
                                          unsigned short* __restrict__ xt,
                                          f32x4 acc[4][4],
                                          int ih0, int iw0, int lane, int wv) {
    constexpr int K2 = K * K;
    constexpr int TS = 31 + (K - 1) * D;
    constexpr int SLOTS = (TS + 1) / 2;
    constexpr int HPW = SLOTS * 8;
    constexpr int PITCH = 2 * HPW;
    constexpr int NRC = (TS + 1) / 2;
    int p = lane & 15, hi = lane >> 4;

#pragma unroll 1
    for (int cb = 0; cb < 8; ++cb) {
        __syncthreads();
        const float* xc8 = xb + (size_t)cb * 8 * (HH * WW);
        const unsigned short* xbb = xbf_b + (size_t)cb * (HH * WW) * 8;
        if (EVEN) stage_even<NRC, PRE>(xc8, xbb, ih0, iw0, xt, lane, wv);
        else      stage_full<TS, HPW, PRE>(xc8, xbb, ih0, iw0, xt, lane, wv);
        __syncthreads();
        const unsigned short* wcb = wq + (size_t)cb * GE * 2048;
#pragma unroll 2
        for (int g = 0; g < GE; ++g) {
            int tap = g * 4 + hi;
            int tapc = tap < K2 ? tap : K2 - 1;  // dummy taps carry zero weights
            int kh = tapc / K, kw = tapc % K;
            const unsigned short* wg = wcb + g * 2048 + hi * 512;
            bf16x8 a0 = *reinterpret_cast<const bf16x8*>(wg + p * 8);
            bf16x8 a1 = *reinterpret_cast<const bf16x8*>(wg + 128 + p * 8);
            bf16x8 a2 = *reinterpret_cast<const bf16x8*>(wg + 256 + p * 8);
            bf16x8 a3 = *reinterpret_cast<const bf16x8*>(wg + 384 + p * 8);
            if (EVEN) {
                constexpr int DH = D / 2;
                int ec = p + DH * kw;
                int erb = wv * 4 + DH * kh;
#pragma unroll
                for (int j = 0; j < 4; ++j) {
                    const bf16x8 bf = *reinterpret_cast<const bf16x8*>(
                        &xt[((erb + j) * NRC + ec) * 8]);
                    acc[j][0] = __builtin_amdgcn_mfma_f32_16x16x32_bf16(a0, bf, acc[j][0], 0, 0, 0);
                    acc[j][1] = __builtin_amdgcn_mfma_f32_16x16x32_bf16(a1, bf, acc[j][1], 0, 0, 0);
                    acc[j][2] = __builtin_amdgcn_mfma_f32_16x16x32_bf16(a2, bf, acc[j][2], 0, 0, 0);
                    acc[j][3] = __builtin_amdgcn_mfma_f32_16x16x32_bf16(a3, bf, acc[j][3], 0, 0, 0);
                }
            } else {
                int ic = 2 * p + D * kw;
                int bbase = (ic & 1) * HPW + (ic >> 1) * 8;
                int irb = D * kh + wv * 8;
#pragma unroll
                for (int j = 0; j < 4; ++j) {
                    const bf16x8 bf = *reinterpret_cast<const bf16x8*>(
                        &xt[(irb + 2 * j) * PITCH + bbase]);
                    acc[j][0] = __builtin_amdgcn_mfma_f32_16x16x32_bf16(a0, bf, acc[j][0], 0, 0, 0);
                    acc[j][1] = __builtin_amdgcn_mfma_f32_16x16x32_bf16(a1, bf, acc[j][1], 0, 0, 0);
                    acc[j][2] = __builtin_amdgcn_mfma_f32_16x16x32_bf16(a2, bf, acc[j][2], 0, 0, 0);
                    acc[j][3] = __builtin_amdgcn_mfma_f32_16x16x32_bf16(a3, bf, acc[j][3], 0, 0, 0);
                }
            }
        }
    }
}

// ---------------- unified MoE conv + BN + GELU + gate ----------------
template <bool PRE>
__global__ __launch_bounds__(256, 4)
void conv_moe_kernel(const float* __restrict__ x, const unsigned short* __restrict__ xbf,
                     const unsigned short* __restrict__ wq0,
                     const unsigned short* __restrict__ wq1,
                     const unsigned short* __restrict__ wq2,
                     const unsigned short* __restrict__ wq3,
                     const float* __restrict__ b0_, const float* __restrict__ b1_,
                     const float* __restrict__ b2_, const float* __restrict__ b3_,
                     const float* __restrict__ bns, const float* __restrict__ bnb,
                     const float* __restrict__ bnm, const float* __restrict__ bnv,
                     const int* __restrict__ sel_idx, const float* __restrict__ sel_w,
                     const int* __restrict__ ord, float* __restrict__ out) {
    __shared__ __align__(16) unsigned short xt[19600];  // K=7 worst case: 49*400

    int bidx = blockIdx.x;
    int bs = ord[bidx >> 6];  // LPT: heavy experts first
    int tile = bidx & 63;
    int b = bs >> 1, slot = bs & 1;
    int e = sel_idx[bs];
    float gwt = sel_w[bs];
    int oh0 = (tile >> 3) * 16, ow0 = (tile & 7) * 16;
    const float* xb = x + (size_t)b * CIN * HH * WW;
    const unsigned short* xbf_b = xbf + (size_t)b * CIN * (HH * WW);
    int lane = threadIdx.x & 63, wv = threadIdx.x >> 6;
    int p = lane & 15, hi = lane >> 4;

    f32x4 acc[4][4];
#pragma unroll
    for (int j = 0; j < 4; ++j)
#pragma unroll
        for (int ct = 0; ct < 4; ++ct) acc[j][ct] = (f32x4){0.f, 0.f, 0.f, 0.f};

    switch (e) {
        case 0:
            conv_body<3, 1, 3, false, PRE>(xb, xbf_b, wq0, xt, acc, oh0 * 2 - 1, ow0 * 2 - 1, lane, wv);
            break;
        case 1:
            conv_body<5, 2, 7, true, PRE>(xb, xbf_b, wq1, xt, acc, oh0 * 2 - 4, ow0 * 2 - 4, lane, wv);
            break;
        case 2:
            conv_body<7, 3, 13, false, PRE>(xb, xbf_b, wq2, xt, acc, oh0 * 2 - 9, ow0 * 2 - 9, lane, wv);
            break;
        default:
            conv_body<9, 4, 21, true, PRE>(xb, xbf_b, wq3, xt, acc, oh0 * 2 - 16, ow0 * 2 - 16, lane, wv);
            break;
    }

    const float* be = (e == 0) ? b0_ : (e == 1) ? b1_ : (e == 2) ? b2_ : b3_;
    float* ob = out + (size_t)(b * 128 + slot * 64) * (OHW * OHW);
#pragma unroll
    for (int ct = 0; ct < 4; ++ct) {
#pragma unroll
        for (int reg = 0; reg < 4; ++reg) {
            int co = ct * 16 + hi * 4 + reg;
            float bias = be[co];
            float sc = bns[e * CE + co], bi = bnb[e * CE + co];
            float mn = bnm[e * CE + co], vr = bnv[e * CE + co];
            float inv = sc * rsqrtf(vr + 1e-5f);
            float beta = bi - mn * inv + bias * inv;
#pragma unroll
            for (int j = 0; j < 4; ++j) {
                float y = acc[j][ct][reg] * inv + beta;
                float gl = 0.5f * y * (1.0f + erff(y * 0.70710678118654752f));
                int oh = oh0 + wv * 4 + j, ow = ow0 + p;
                ob[(size_t)co * (OHW * OHW) + oh * OHW + ow] = gl * gwt;
            }
        }
    }
}

extern "C" void kernel_launch(void* const* d_in, const int* in_sizes, int n_in,
                              void* d_out, int out_size, void* d_ws, size_t ws_size,
                              hipStream_t stream) {
    const float* x   = (const float*)d_in[0];
    const float* w0  = (const float*)d_in[1];
    const float* b0  = (const float*)d_in[2];
    const float* w1  = (const float*)d_in[3];
    const float* b1  = (const float*)d_in[4];
    const float* w2  = (const float*)d_in[5];
    const float* b2  = (const float*)d_in[6];
    const float* w3  = (const float*)d_in[7];
    const float* b3  = (const float*)d_in[8];
    const float* bns = (const float*)d_in[9];
    const float* bnb = (const float*)d_in[10];
    const float* bnm = (const float*)d_in[11];
    const float* bnv = (const float*)d_in[12];
    const float* gw  = (const float*)d_in[13];
    const float* gb  = (const float*)d_in[14];
    float* out = (float*)d_out;

    char* ws = (char*)d_ws;
    float* partial = (float*)ws;                         // 16*8*8*8 f32 = 32768 B
    int* sel_idx   = (int*)(ws + 32768);                 // 128 B
    float* sel_w   = (float*)(ws + 32896);               // 128 B
    int* ord       = (int*)(ws + 33024);                 // 128 B
    unsigned short* wq = (unsigned short*)(ws + 33280);  // bf16 packed weights
    unsigned short* wq0 = wq;             // GE=3  (49152 shorts)
    unsigned short* wq1 = wq + 49152;     // GE=7  (114688)
    unsigned short* wq2 = wq + 163840;    // GE=13 (212992)
    unsigned short* wq3 = wq + 376832;    // GE=21 (344064)
    unsigned short* xbf = (unsigned short*)(ws + 2097152);  // bf16 NHWC8 x, 134217728 B
    const size_t NEED = 2097152ull + 134217728ull;
    bool pre = ws_size >= NEED;

    if (pre) poolcvt_kernel<true><<<dim3(128, 8), 256, 0, stream>>>(x, xbf, partial);
    else     poolcvt_kernel<false><<<dim3(128, 8), 256, 0, stream>>>(x, xbf, partial);
    gate_kernel<<<dim3(16), 64, 0, stream>>>(partial, gw, gb, sel_idx, sel_w);
    order_kernel<<<dim3(1), 64, 0, stream>>>(sel_idx, ord);

    wprep_kernel<3, 3><<<dim3(8, 3), 256, 0, stream>>>(w0, wq0);
    wprep_kernel<5, 7><<<dim3(8, 7), 256, 0, stream>>>(w1, wq1);
    wprep_kernel<7, 13><<<dim3(8, 13), 256, 0, stream>>>(w2, wq2);
    wprep_kernel<9, 21><<<dim3(8, 21), 256, 0, stream>>>(w3, wq3);

    if (pre)
        conv_moe_kernel<true><<<dim3(2048), 256, 0, stream>>>(
            x, xbf, wq0, wq1, wq2, wq3, b0, b1, b2, b3, bns, bnb, bnm, bnv,
            sel_idx, sel_w, ord, out);
    else
        conv_moe_kernel<false><<<dim3(2048), 256, 0, stream>>>(
            x, xbf, wq0, wq1, wq2, wq3, b0, b1, b2, b3, bns, bnb, bnm, bnv,
            sel_idx, sel_w, ord, out);
}